// Round 4
// baseline (284.246 us; speedup 1.0000x reference)
//
#include <hip/hip_runtime.h>
#include <hip/hip_bf16.h>
#include <stdint.h>

// Problem constants
#define NLAYERS 32
#define DSIZE   1024
#define OSIZE   1024
#define BATCH   32
#define SEQ     256

// ws layout (ints): [0]=ntiles; [16..272)=perm; [512 + 4*t ..]=tile{layer, rank_base, nranks, pad}
#define WS_PERM  16
#define WS_TILE  512
#define MAX_TILES 88   // sum ceil(cnt/4) <= 64 + 24 = 88

typedef __attribute__((ext_vector_type(8)))  short short8;
typedef __attribute__((ext_vector_type(16))) float f32x16;

#define LDSTRIDE 40   // shorts per LDS row (32 + 8 pad; 80 B = 16B multiple for b128)
#define BK 32
#define KSPLIT 2      // two K-halves of 512, fp32 atomicAdd into zeroed d_out

__global__ void prep_kernel(const int* __restrict__ layer_idx, int* __restrict__ wsi) {
    __shared__ int cnt[NLAYERS];
    __shared__ int start_[NLAYERS];
    __shared__ int cursor[NLAYERS];
    const int t = threadIdx.x;
    if (t < NLAYERS) cnt[t] = 0;
    __syncthreads();
    int l = 0;
    if (t < SEQ) { l = layer_idx[t]; atomicAdd(&cnt[l], 1); }
    __syncthreads();
    if (t == 0) {
        int acc = 0;
        for (int i = 0; i < NLAYERS; ++i) { start_[i] = acc; cursor[i] = acc; acc += cnt[i]; }
    }
    __syncthreads();
    if (t < SEQ) {
        int r = atomicAdd(&cursor[l], 1);
        wsi[WS_PERM + r] = t;           // perm[rank] = s
    }
    if (t == 0) {
        int nt = 0;
        for (int i = 0; i < NLAYERS; ++i) {
            const int c = cnt[i];
            for (int j = 0; j < c; j += 4) {
                wsi[WS_TILE + nt*4 + 0] = i;
                wsi[WS_TILE + nt*4 + 1] = start_[i] + j;
                wsi[WS_TILE + nt*4 + 2] = (c - j < 4) ? (c - j) : 4;
                ++nt;
            }
        }
        wsi[0] = nt;
    }
}

// round-to-nearest fp32->bf16 pair pack: low16 = bf16(a), high16 = bf16(b)
static __device__ __forceinline__ unsigned pk2(float a, float b) {
    unsigned ua = __builtin_bit_cast(unsigned, a) + 0x8000u;
    unsigned ub = __builtin_bit_cast(unsigned, b) + 0x8000u;
    return __builtin_amdgcn_perm(ub, ua, 0x07060302u);  // {ua[2],ua[3],ub[2],ub[3]}
}

// Tile: M=128 (4 ranks x 32 batch) x N=128, K=512 per split (BK=32, 16 iters).
// 4 waves; wave wv computes rows [32wv, 32wv+32) x all 128 cols (rank == wv).
__global__ __launch_bounds__(256, 4) void gemm_kernel(
        const float* __restrict__ x, const float* __restrict__ wgt,
        const int* __restrict__ wsi, float* __restrict__ out) {
    const int ntiles = wsi[0];
    const int mt = blockIdx.y;
    if (mt >= ntiles) return;
    const int layer     = wsi[WS_TILE + mt*4 + 0];
    const int rank_base = wsi[WS_TILE + mt*4 + 1];
    const int nranks    = wsi[WS_TILE + mt*4 + 2];
    const int ntile     = blockIdx.x;               // 0..7 -> o block of 128
    const int koff      = blockIdx.z * (DSIZE / KSPLIT);  // 0 or 512

    __shared__ __align__(16) short ldsA[128 * LDSTRIDE];
    __shared__ __align__(16) short ldsB[128 * LDSTRIDE];

    const int t     = threadIdx.x;
    // staging: BK=32 floats/row = 8 lanes x 16B; wave covers 8 rows/instr (8x128B segs)
    const int c4    = (t & 7) * 4;   // float (== bf16-short) column within 32-wide k-slab
    const int rbase = t >> 3;        // 0..31; pass p covers row = rbase + 32*p

    bool svalid[4];
    int  sv[4];
    #pragma unroll
    for (int j = 0; j < 4; ++j) {
        svalid[j] = (j < nranks);
        sv[j] = svalid[j] ? wsi[WS_PERM + rank_base + j] : 0;
    }

    // A rows: row = rbase + 32p -> rank = p, batch b = rbase
    const float* aptr[4];
    #pragma unroll
    for (int p = 0; p < 4; ++p)
        aptr[p] = x + (((size_t)(rbase * SEQ + sv[p])) << 10) + koff + c4;
    // B rows: orow = ntile*128 + rbase + 32p
    const float* bbase = wgt + (((size_t)((layer << 10) + ntile * 128 + rbase)) << 10) + koff + c4;

    float4 ra[4], rb[4];
    auto load_step = [&](int kk) {
        #pragma unroll
        for (int p = 0; p < 4; ++p) {
            if (svalid[p]) ra[p] = *(const float4*)(aptr[p] + kk);
            else           ra[p] = make_float4(0.f, 0.f, 0.f, 0.f);
        }
        #pragma unroll
        for (int p = 0; p < 4; ++p)
            rb[p] = *(const float4*)(bbase + ((size_t)(32 * p) << 10) + kk);
    };

    // compute-side mapping
    const int lane = t & 63;
    const int wv   = t >> 6;
    const int wm   = wv * 32;       // wave m-row base == rank wv
    const int l31  = lane & 31;
    const int lh   = lane >> 5;

    f32x16 acc[4];
    #pragma unroll
    for (int ni = 0; ni < 4; ++ni)
        #pragma unroll
        for (int r = 0; r < 16; ++r) acc[ni][r] = 0.f;

    const short* pA0 = &ldsA[(wm + l31) * LDSTRIDE + lh * 8];
    const short* pB0 = &ldsB[l31 * LDSTRIDE + lh * 8];

    load_step(0);
    #pragma unroll 1
    for (int kk = 0; kk < DSIZE / KSPLIT; kk += BK) {
        __syncthreads();   // previous compute done reading LDS
        #pragma unroll
        for (int p = 0; p < 4; ++p) {
            const int row = rbase + 32 * p;
            uint2 va;
            va.x = pk2(ra[p].x, ra[p].y);
            va.y = pk2(ra[p].z, ra[p].w);
            *(uint2*)&ldsA[row * LDSTRIDE + c4] = va;
        }
        #pragma unroll
        for (int p = 0; p < 4; ++p) {
            const int row = rbase + 32 * p;
            uint2 vb;
            vb.x = pk2(rb[p].x, rb[p].y);
            vb.y = pk2(rb[p].z, rb[p].w);
            *(uint2*)&ldsB[row * LDSTRIDE + c4] = vb;
        }
        __syncthreads();
        if (kk + BK < DSIZE / KSPLIT) load_step(kk + BK);  // prefetch overlaps MFMA
        #pragma unroll
        for (int sub = 0; sub < 2; ++sub) {                // 2 x (K=16) sub-steps
            short8 a0 = *(const short8*)(pA0 + sub*16);
            #pragma unroll
            for (int ni = 0; ni < 4; ++ni) {
                short8 b = *(const short8*)(pB0 + 32*ni*LDSTRIDE + sub*16);
                acc[ni] = __builtin_amdgcn_mfma_f32_32x32x16_bf16(a0, b, acc[ni], 0, 0, 0);
            }
        }
    }

    // epilogue: C/D layout col(l31)=ocol, row(reg,lh)=batch; atomicAdd (split-K)
    if (wv < nranks) {
        const int s = sv[wv];
        #pragma unroll
        for (int ni = 0; ni < 4; ++ni) {
            const int ocol = ntile * 128 + ni * 32 + l31;
            #pragma unroll
            for (int r = 0; r < 16; ++r) {
                const int brow = (r & 3) + 8 * (r >> 2) + 4 * lh;  // = batch b
                atomicAdd(&out[(((size_t)(brow * SEQ + s)) << 10) + ocol], acc[ni][r]);
            }
        }
    }
}

extern "C" void kernel_launch(void* const* d_in, const int* in_sizes, int n_in,
                              void* d_out, int out_size, void* d_ws, size_t ws_size,
                              hipStream_t stream) {
    const float* x         = (const float*)d_in[0];
    const int*   layer_idx = (const int*)  d_in[1];
    const float* weight    = (const float*)d_in[2];
    float* out = (float*)d_out;
    int*   wsi = (int*)d_ws;

    hipMemsetAsync(out, 0, (size_t)out_size * sizeof(float), stream);
    prep_kernel<<<1, 256, 0, stream>>>(layer_idx, wsi);
    gemm_kernel<<<dim3(8, MAX_TILES, KSPLIT), 256, 0, stream>>>(x, weight, wsi, out);
}